// Round 14
// baseline (250.540 us; speedup 1.0000x reference)
//
#include <hip/hip_runtime.h>

// DCNv4 on gfx950 — bf16 MFMA pipeline, fragment-swizzled operands.
// R21: oms 4-g blocks to cut the dominant L2/L3 stream.
//  Evidence: R20's oms regressed 57.8->76.6us with IDENTICAL code/FETCH/
//  conflicts and LOWER VALUBusy -> stalls moved into L2/L3. Arithmetic:
//  32 g-blocks x 512KB xdwF quarter-slice = 512 MB L2/L3 traffic per
//  dispatch (the shared-bandwidth limiter that made R14 TLP and R15 ILP
//  null). Fix: 4 g per block -> xdwF stream 512->128 MB, value_g staging
//  64->21 MB. s_v = 4 band windows (20x66, R10-verified band+clamp),
//  s_om unchanged; LDS 150KB -> 1 blk/CU; grid 256 (img in low bits).
//  Per-g MFMA->s_om->sample pipeline byte-identical, serial x4.
// KW: vp/op frag-swizzle + per-g padded om_wG
// KF: dwconv3x3 + value GEMM -> s_xdw/s_xf staged, coalesced stores (R20)
// OMS: 4x per block: om GEMM (B in regs) -> s_om -> 2-px scalar sampling
// K4: out = sampledF @ op_wF (M=128, B in LDS, fp32 NHWC out)

typedef __bf16 bf16_t;
typedef bf16_t bf16x8 __attribute__((ext_vector_type(8)));
typedef bf16_t bf16x4 __attribute__((ext_vector_type(4)));
typedef float f32x4 __attribute__((ext_vector_type(4)));

namespace {
constexpr int NN = 8, HH = 64, WW = 64, CC = 256;
constexpr int G = 32, GC = 8;
constexpr int NPIX = NN * HH * WW;            // 32768
}

// fragment-swizzled flat index for a [rows][256] bf16 matrix
__device__ __forceinline__ size_t fragIdx(int row, int c) {
  return ((size_t)(row >> 4) * 4096) + ((c >> 5) * 512) + (((c >> 3) & 3) * 128) +
         ((row & 15) * 8) + (c & 7);
}

// ---------------- KW: weights -> bf16 fragment layouts ----------------------
__global__ __launch_bounds__(256) void convert_weights_kernel(
    const float* __restrict__ om_w, const float* __restrict__ vp_w,
    const float* __restrict__ op_w, bf16_t* __restrict__ om_wG,
    bf16_t* __restrict__ vp_wF, bf16_t* __restrict__ op_wF) {
  __shared__ float s_t[64][65];
  __shared__ float s_w[256][27];
  const int b = blockIdx.x, t = threadIdx.x;
  if (b < 32) {
    const float* src;
    bf16_t* dst;
    int kt, nt;
    if (b < 16) { src = vp_w; dst = vp_wF; kt = b >> 2; nt = b & 3; }
    else        { src = op_w; dst = op_wF; kt = (b - 16) >> 2; nt = (b - 16) & 3; }
    const int nl = t & 63, kh = t >> 6;
    const int n = nt * 64 + nl;
#pragma unroll
    for (int i = 0; i < 16; ++i) {
      const int kl = kh * 16 + i;
      s_t[kl][nl] = src[(size_t)(kt * 64 + kl) * CC + n];
    }
    __syncthreads();
    const int lane = t & 63, kq = lane >> 4, n15 = lane & 15, n16 = t >> 6;
#pragma unroll
    for (int it = 0; it < 2; ++it) {
      bf16x8 v;
#pragma unroll
      for (int j = 0; j < 8; ++j)
        v[j] = (bf16_t)s_t[it * 32 + kq * 8 + j][n16 * 16 + n15];
      const size_t off = (size_t)(nt * 4 + n16) * 4096 + (size_t)(kt * 2 + it) * 512 +
                         kq * 128 + n15 * 8;
      *(bf16x8*)(dst + off) = v;
    }
  } else {
    const int g = b - 32;
#pragma unroll
    for (int j = 0; j < 27; ++j) s_w[t][j] = om_w[(size_t)t * 864 + g * 27 + j];
    __syncthreads();
#pragma unroll
    for (int i = 0; i < 4; ++i) {
      const int chunk = i * 256 + t;  // 1024 chunks of 8 bf16
      const int tile = chunk >> 9, ks = (chunk >> 6) & 7, kq = (chunk >> 4) & 3,
                n15 = chunk & 15;
      const int j = tile * 16 + n15;
      bf16x8 v;
#pragma unroll
      for (int cl = 0; cl < 8; ++cl) {
        const int c = ks * 32 + kq * 8 + cl;
        v[cl] = (j < 27) ? (bf16_t)s_w[c][j] : (bf16_t)0.0f;
      }
      *(bf16x8*)(om_wG + ((size_t)g << 13) + (size_t)chunk * 8) = v;
    }
  }
}

// ---------------- KF: fused dwconv3x3 + value GEMM; block = one image row ----
__global__ __launch_bounds__(512, 2) void dwconv_value_kernel(
    const float* __restrict__ x, const float* __restrict__ dw_w,
    const float* __restrict__ dw_b, const bf16_t* __restrict__ vp_wF,
    const float* __restrict__ vp_b, bf16_t* __restrict__ xdwF,
    bf16_t* __restrict__ value_g) {
  __shared__ bf16_t s_xf[64 * 256];   // x bf16 frags; reused as rotated s_out
  __shared__ bf16_t s_xdw[64 * 256];  // xdw bf16 frags (staged, coalesced out)

  const int t = threadIdx.x;
  const int row = blockIdx.x;        // img*64 + y
  const int y = row & 63;
  const int img = row >> 6;

  // ---- Phase A: dwconv -> s_xdw (LDS only; no global stores)
  {
    const int cq = (t & 63) * 4;   // channel base
    const int seg = t >> 6;        // 8-px segment
    const bool up = (y > 0), dn = (y < HH - 1);
    const float* xrow = x + (size_t)row * WW * CC + cq;

    const float4 bias = *(const float4*)&dw_b[cq];
    float4 dw[9];
#pragma unroll
    for (int i = 0; i < 9; ++i) dw[i] = *(const float4*)&dw_w[(size_t)i * CC + cq];

    const float4 zero = make_float4(0.f, 0.f, 0.f, 0.f);
    auto loadcol = [&](int xx, float4 c[3]) {
      if (xx < 0 || xx >= WW) { c[0] = c[1] = c[2] = zero; return; }
      c[0] = up ? *(const float4*)(xrow + ((size_t)xx - WW) * CC) : zero;
      c[1] = *(const float4*)(xrow + (size_t)xx * CC);
      c[2] = dn ? *(const float4*)(xrow + ((size_t)xx + WW) * CC) : zero;
    };

    const int x0 = seg * 8;
    float4 cm[3], cc[3], cp[3];
    loadcol(x0 - 1, cm);
    loadcol(x0, cc);

    for (int xx = x0; xx < x0 + 8; ++xx) {
      loadcol(xx + 1, cp);
      float4 a = bias;
#pragma unroll
      for (int r = 0; r < 3; ++r) {
        const float4 w0 = dw[r * 3 + 0], w1 = dw[r * 3 + 1], w2 = dw[r * 3 + 2];
        a.x = fmaf(cm[r].x, w0.x, fmaf(cc[r].x, w1.x, fmaf(cp[r].x, w2.x, a.x)));
        a.y = fmaf(cm[r].y, w0.y, fmaf(cc[r].y, w1.y, fmaf(cp[r].y, w2.y, a.y)));
        a.z = fmaf(cm[r].z, w0.z, fmaf(cc[r].z, w1.z, fmaf(cp[r].z, w2.z, a.z)));
        a.w = fmaf(cm[r].w, w0.w, fmaf(cc[r].w, w1.w, fmaf(cp[r].w, w2.w, a.w)));
      }
      bf16x4 av, cv;
      av[0] = (bf16_t)a.x; av[1] = (bf16_t)a.y; av[2] = (bf16_t)a.z; av[3] = (bf16_t)a.w;
      cv[0] = (bf16_t)cc[1].x; cv[1] = (bf16_t)cc[1].y;
      cv[2] = (bf16_t)cc[1].z; cv[3] = (bf16_t)cc[1].w;
      const int lf = (xx >> 4) * 4096 + ((cq >> 5) * 512) + (((cq >> 3) & 3) * 128) +
                     ((xx & 15) * 8) + (cq & 7);
      *(bf16x4*)&s_xdw[lf] = av;
      *(bf16x4*)&s_xf[lf] = cv;
#pragma unroll
      for (int r = 0; r < 3; ++r) { cm[r] = cc[r]; cc[r] = cp[r]; }
    }
  }
  __syncthreads();

  // ---- cooperative coalesced xdwF store (2048 x 16B linear)
  {
    const bf16x8* src = (const bf16x8*)s_xdw;
    bf16x8* dst = (bf16x8*)(xdwF + (size_t)row * 16384);
#pragma unroll
    for (int i = 0; i < 4; ++i) {
      const int idx = i * 512 + t;
      dst[idx] = src[idx];
    }
  }

  // ---- Phase B: value GEMM (M=64 from LDS, N=256)
  {
    const int lane = t & 63;
    const int wave = t >> 6;
    const int mq = wave >> 1;      // m-tile 0..3
    const int nh = wave & 1;       // n-half
    const int m = lane & 15;
    const int kq = lane >> 4;

    const bf16_t* Ap = s_xf + mq * 4096 + lane * 8;
    const bf16_t* Bp = vp_wF + (size_t)(nh * 8) * 4096 + lane * 8;

    f32x4 acc[8] = {};
#pragma unroll
    for (int ks = 0; ks < 8; ++ks) {
      const bf16x8 a = *(const bf16x8*)(Ap + ks * 512);
#pragma unroll
      for (int i = 0; i < 8; ++i) {
        const bf16x8 b = *(const bf16x8*)(Bp + (size_t)i * 4096 + ks * 512);
        acc[i] = __builtin_amdgcn_mfma_f32_16x16x32_bf16(a, b, acc[i], 0, 0, 0);
      }
    }

    __syncthreads();   // all waves done reading s_xf; safe to overwrite

    // rotated staging: s_out[px][((g+px)&31)*8 + c] (read-side conflict-free)
    bf16_t* s_out = s_xf;
#pragma unroll
    for (int i = 0; i < 8; ++i) {
      const int n = (nh * 8 + i) * 16 + m;
      const float bs = vp_b[n];
      const int g = n >> 3, c = n & 7;
#pragma unroll
      for (int r = 0; r < 4; ++r) {
        const int pl = mq * 16 + kq * 4 + r;           // pixel local 0..63
        s_out[pl * 256 + (((g + pl) & 31) << 3) + c] = (bf16_t)(acc[i][r] + bs);
      }
    }
  }
  __syncthreads();

  // ---- cooperative coalesced value_g store: chunk = g*64+px -> 1KB runs/g
  {
    const bf16x8* s16 = (const bf16x8*)s_xf;
    bf16x8* dst = (bf16x8*)value_g;
#pragma unroll
    for (int i = 0; i < 4; ++i) {
      const int chunk = i * 512 + t;       // 0..2047
      const int g = chunk >> 6, px = chunk & 63;
      const bf16x8 v = s16[px * 32 + ((g + px) & 31)];
      dst[((size_t)(img * G + g) << 12) + y * 64 + px] = v;
    }
  }
}

// ---------------- OMS: 4-g blocks; block = (img, g-quad, quarter) -----------
// grid b: img = b&7 (XCD affinity), gq = (b>>3)&7, quarter = b>>6. 256 blocks.
// s_v: 4 band windows (rows y0-2..y0+17, cols -1..64, zero outside; R10's
// verified band+clamp). LDS 150KB -> 1 block/CU. xdwF L2 stream 512->128 MB.
__global__ __launch_bounds__(512, 2) void oms_kernel(
    const bf16_t* __restrict__ xdwF, const bf16_t* __restrict__ om_wG,
    const float* __restrict__ om_b, const bf16_t* __restrict__ value_g,
    bf16_t* __restrict__ sampledF) {
  __shared__ bf16x8 s_v[4][20 * 66];       // 84,480 B: 4 band windows
  __shared__ bf16_t s_om[8][4][128][8];    // 65,536 B chunk-major, p-stride 16B

  const int t = threadIdx.x;
  const int lane = t & 63, wave = t >> 6;  // wave 0..7
  const int b = blockIdx.x;
  const int img = b & 7, gq = (b >> 3) & 7, quarter = b >> 6;
  const int c15 = lane & 15, kq = lane >> 4;
  const int tile0 = img * 256 + quarter * 64;   // global 16-px-tile base
  const int y0 = quarter * 16;

  // ---- stage 4 band windows
  {
    const bf16x8 zv = {};
    for (int i = t; i < 4 * 1320; i += 512) {
      const int gh = i / 1320;
      const int r = i - gh * 1320;
      const int wr = r / 66;
      const int cx = r - wr * 66;
      const int yr = y0 - 2 + wr;
      bf16x8 v = zv;
      if (yr >= 0 && yr < HH && cx >= 1 && cx <= 64) {
        const int g = gq * 4 + gh;
        v = ((const bf16x8*)(value_g + ((size_t)(img * G + g) << 15)))[yr * 64 + cx - 1];
      }
      s_v[gh][r] = v;
    }
  }

  bool first = true;
#pragma unroll 1
  for (int gh = 0; gh < 4; ++gh) {
    const int g = gq * 4 + gh;

    // ---- B-frags + bias for this g
    bf16x8 wf[2][8];
    {
      const bf16_t* base = om_wG + ((size_t)g << 13) + (size_t)lane * 8;
#pragma unroll
      for (int n2 = 0; n2 < 2; ++n2)
#pragma unroll
        for (int ks = 0; ks < 8; ++ks)
          wf[n2][ks] = *(const bf16x8*)(base + n2 * 4096 + ks * 512);
    }
    float bias[2][4];
#pragma unroll
    for (int n2 = 0; n2 < 2; ++n2)
#pragma unroll
      for (int r = 0; r < 4; ++r) {
        const int j = n2 * 16 + kq * 4 + r;
        bias[n2][r] = (j < 27) ? om_b[g * 27 + j] : 0.0f;
      }

    // ---- om GEMM: 8 tiles/wave -> s_om[wave] (D[j][px], bf16, chunk-major)
    {
      const int tb = tile0 + wave * 8;
#pragma unroll
      for (int q = 0; q < 8; ++q) {
        const bf16_t* Ap = xdwF + ((size_t)(tb + q)) * 4096 + (size_t)lane * 8;
        f32x4 a0 = {}, a1 = {};
#pragma unroll
        for (int ks = 0; ks < 8; ++ks) {
          const bf16x8 xf = *(const bf16x8*)(Ap + ks * 512);
          a0 = __builtin_amdgcn_mfma_f32_16x16x32_bf16(wf[0][ks], xf, a0, 0, 0, 0);
          a1 = __builtin_amdgcn_mfma_f32_16x16x32_bf16(wf[1][ks], xf, a1, 0, 0, 0);
        }
        const int p = q * 16 + c15;
        bf16x4 b0, b1;
#pragma unroll
        for (int r = 0; r < 4; ++r) {
          b0[r] = (bf16_t)(a0[r] + bias[0][r]);
          b1[r] = (bf16_t)(a1[r] + bias[1][r]);
        }
        *(bf16x4*)&s_om[wave][kq >> 1][p][(kq & 1) * 4] = b0;
        *(bf16x4*)&s_om[wave][2 + (kq >> 1)][p][(kq & 1) * 4] = b1;
      }
    }
    if (first) { __syncthreads(); first = false; }  // s_v ready (uniform)

    // ---- sampling: 2 px/thread, scalar cvt+fmaf, band-clamped y
    {
      const int pinA = quarter * 1024 + wave * 128 + lane;  // in-image px
      const int pinB = pinA + 64;
      float arrA[27], arrB[27];
#pragma unroll
      for (int c = 0; c < 4; ++c) {
        const bf16x8 oA = *(const bf16x8*)&s_om[wave][c][lane][0];
        const bf16x8 oB = *(const bf16x8*)&s_om[wave][c][64 + lane][0];
#pragma unroll
        for (int j = 0; j < 8; ++j) {
          const int idx = c * 8 + j;
          if (idx < 27) { arrA[idx] = (float)oA[j]; arrB[idx] = (float)oB[j]; }
        }
      }
      const int xw = lane;
      const int yA = (pinA >> 6) & 63;
      const int yB = yA + 1;

      float accA[GC], accB[GC];
#pragma unroll
      for (int c = 0; c < GC; ++c) { accA[c] = 0.0f; accB[c] = 0.0f; }

      const bf16x8* vband = s_v[gh];
      auto tap = [&](const float* arr, const int y, float* acc, const int k) {
        const float pxf = (float)(xw + (k % 3) - 1) + arr[2 * k];
        const float pyf = (float)(y + (k / 3) - 1) + arr[2 * k + 1];
        const float mk = arr[18 + k];
        const float x0f = floorf(pxf), y0f = floorf(pyf);
        const float tx = pxf - x0f, ty = pyf - y0f;
        const int ix = (int)x0f, iy = (int)y0f;

        // x: clamp to padded [-1,64]; y: clamp to band window [0,19]
        const int iX0 = min(max(ix, -1), 64) + 1;
        const int iX1 = min(max(ix + 1, -1), 64) + 1;
        const int riy = iy - y0 + 2;
        const int iY0 = min(max(riy, 0), 19);
        const int iY1 = min(max(riy + 1, 0), 19);

        const bf16x8 v00 = vband[iY0 * 66 + iX0];
        const bf16x8 v01 = vband[iY0 * 66 + iX1];
        const bf16x8 v10 = vband[iY1 * 66 + iX0];
        const bf16x8 v11 = vband[iY1 * 66 + iX1];

        const float w00 = mk * (1.0f - ty) * (1.0f - tx);
        const float w01 = mk * (1.0f - ty) * tx;
        const float w10 = mk * ty * (1.0f - tx);
        const float w11 = mk * ty * tx;

#pragma unroll
        for (int c = 0; c < GC; ++c) {
          float s = acc[c];
          s = fmaf(w00, (float)v00[c], s);
          s = fmaf(w01, (float)v01[c], s);
          s = fmaf(w10, (float)v10[c], s);
          s = fmaf(w11, (float)v11[c], s);
          acc[c] = s;
        }
      };

#pragma unroll
      for (int k = 0; k < 9; ++k) {
        tap(arrA, yA, accA, k);
        tap(arrB, yB, accB, k);
      }

      bf16x8 svA, svB;
#pragma unroll
      for (int c = 0; c < GC; ++c) {
        svA[c] = (bf16_t)accA[c];
        svB[c] = (bf16_t)accB[c];
      }
      *(bf16x8*)(sampledF + fragIdx(img * 4096 + pinA, g * 8)) = svA;
      *(bf16x8*)(sampledF + fragIdx(img * 4096 + pinB, g * 8)) = svB;
    }
  }
}

// ---------------- K4: out = sampledF @ op_wF, M=128/block, B in LDS ----------
__global__ __launch_bounds__(1024, 1) void out_gemm_kernel(
    const bf16_t* __restrict__ AF, const bf16_t* __restrict__ BF,
    float* __restrict__ out) {
  __shared__ bf16_t s_b[CC * CC];  // 131,072 B: full B, frag layout (linear copy)

  const int t = threadIdx.x;
  {
    const bf16x8* src = (const bf16x8*)BF;
    bf16x8* dst = (bf16x8*)s_b;
#pragma unroll
    for (int i = 0; i < 8; ++i) dst[i * 1024 + t] = src[i * 1024 + t];
  }
  __syncthreads();

  const int lane = t & 63;
  const int wave = t >> 6;        // 0..15
  const int mq = wave >> 1;       // m-tile 0..7
  const int nh = wave & 1;        // n-half
  const int mt = blockIdx.x * 8 + mq;
  const int m = lane & 15;
  const int kq = lane >> 4;

  const bf16_t* Ap = AF + (size_t)mt * 4096 + lane * 8;
  const bf16_t* Bp = s_b + (size_t)(nh * 8) * 4096 + lane * 8;

  f32x4 acc[8] = {};
#pragma unroll
  for (int ks = 0; ks < 8; ++ks) {
    const bf16x8 a = *(const bf16x8*)(Ap + ks * 512);
#pragma unroll
    for (int i = 0; i < 8; ++i) {
      const bf16x8 b = *(const bf16x8*)(Bp + (size_t)i * 4096 + ks * 512);
      acc[i] = __builtin_amdgcn_mfma_f32_16x16x32_bf16(a, b, acc[i], 0, 0, 0);
    }
  }

#pragma unroll
  for (int i = 0; i < 8; ++i) {
    const int n = (nh * 8 + i) * 16 + m;
#pragma unroll
    for (int r = 0; r < 4; ++r) {
      const int pix = mt * 16 + kq * 4 + r;
      out[(size_t)pix * CC + n] = acc[i][r];
    }
  }
}

extern "C" void kernel_launch(void* const* d_in, const int* in_sizes, int n_in,
                              void* d_out, int out_size, void* d_ws, size_t ws_size,
                              hipStream_t stream) {
  const float* x = (const float*)d_in[0];
  const float* dw_w = (const float*)d_in[1];
  const float* dw_b = (const float*)d_in[2];
  const float* om_w = (const float*)d_in[3];
  const float* om_b = (const float*)d_in[4];
  const float* vp_w = (const float*)d_in[5];
  const float* vp_b = (const float*)d_in[6];
  const float* op_w = (const float*)d_in[7];
  float* out = (float*)d_out;

  // workspace layout (bytes)
  char* ws = (char*)d_ws;
  bf16_t* value_g = (bf16_t*)ws;                      // 16,777,216
  bf16_t* xdwF = (bf16_t*)(ws + 16777216);            // 16,777,216
  bf16_t* sampledF = (bf16_t*)(ws + 33554432);        // 16,777,216
  bf16_t* om_wG = (bf16_t*)(ws + 50331648);           //    524,288
  bf16_t* vp_wF = (bf16_t*)(ws + 50855936);           //    131,072
  bf16_t* op_wF = (bf16_t*)(ws + 50987008);           //    131,072

  convert_weights_kernel<<<64, 256, 0, stream>>>(om_w, vp_w, op_w,
                                                 om_wG, vp_wF, op_wF);
  dwconv_value_kernel<<<NN * HH, 512, 0, stream>>>(x, dw_w, dw_b, vp_wF, vp_b,
                                                   xdwF, value_g);
  oms_kernel<<<256, 512, 0, stream>>>(xdwF, om_wG, om_b, value_g, sampledF);
  out_gemm_kernel<<<NPIX / 128, 1024, 0, stream>>>(sampledF, op_wF, out);
}

// Round 15
// 185.167 us; speedup vs baseline: 1.3530x; 1.3530x over previous
//
#include <hip/hip_runtime.h>

// DCNv4 on gfx950 — bf16 MFMA pipeline, fragment-swizzled operands.
// R22: revert R21 (4-g blocks: FETCH 18.5->219MB, temporal-reuse destroyed,
//  oms 140us) back to R20's exact structure (188.1us best), plus ONE local
//  change: depth-2 register double-buffer on oms's xdwF loads.
//  Evidence: R20 oms = 76.6us, VALU 31%, Mfma 8.6%, FETCH 18.5MB -> stall-
//  bound on xdwF reads from L3/remote-L2 (~200-900cy, data written by KF on
//  other XCDs). Loop was serial per q: 8 loads -> wait -> 16 MFMA. Prefetch
//  q+1's loads under q's MFMAs hides most of the per-batch latency.
//  +64 VGPR (128->~192), still 8 waves/CU (LDS-bound at 135KB).
// KW: vp/op frag-swizzle + per-g padded om_wG
// KF: dwconv3x3 + value GEMM -> s_xdw/s_xf staged, coalesced stores (R20)
// OMS: om GEMM (B in regs, dbuf A) -> s_om -> 2-px scalar sampling (R19/R20)
// K4: out = sampledF @ op_wF (M=128, B in LDS, fp32 NHWC out)

typedef __bf16 bf16_t;
typedef bf16_t bf16x8 __attribute__((ext_vector_type(8)));
typedef bf16_t bf16x4 __attribute__((ext_vector_type(4)));
typedef float f32x4 __attribute__((ext_vector_type(4)));

namespace {
constexpr int NN = 8, HH = 64, WW = 64, CC = 256;
constexpr int G = 32, GC = 8;
constexpr int NPIX = NN * HH * WW;            // 32768
}

// fragment-swizzled flat index for a [rows][256] bf16 matrix
__device__ __forceinline__ size_t fragIdx(int row, int c) {
  return ((size_t)(row >> 4) * 4096) + ((c >> 5) * 512) + (((c >> 3) & 3) * 128) +
         ((row & 15) * 8) + (c & 7);
}

// ---------------- KW: weights -> bf16 fragment layouts ----------------------
__global__ __launch_bounds__(256) void convert_weights_kernel(
    const float* __restrict__ om_w, const float* __restrict__ vp_w,
    const float* __restrict__ op_w, bf16_t* __restrict__ om_wG,
    bf16_t* __restrict__ vp_wF, bf16_t* __restrict__ op_wF) {
  __shared__ float s_t[64][65];
  __shared__ float s_w[256][27];
  const int b = blockIdx.x, t = threadIdx.x;
  if (b < 32) {
    const float* src;
    bf16_t* dst;
    int kt, nt;
    if (b < 16) { src = vp_w; dst = vp_wF; kt = b >> 2; nt = b & 3; }
    else        { src = op_w; dst = op_wF; kt = (b - 16) >> 2; nt = (b - 16) & 3; }
    const int nl = t & 63, kh = t >> 6;
    const int n = nt * 64 + nl;
#pragma unroll
    for (int i = 0; i < 16; ++i) {
      const int kl = kh * 16 + i;
      s_t[kl][nl] = src[(size_t)(kt * 64 + kl) * CC + n];
    }
    __syncthreads();
    const int lane = t & 63, kq = lane >> 4, n15 = lane & 15, n16 = t >> 6;
#pragma unroll
    for (int it = 0; it < 2; ++it) {
      bf16x8 v;
#pragma unroll
      for (int j = 0; j < 8; ++j)
        v[j] = (bf16_t)s_t[it * 32 + kq * 8 + j][n16 * 16 + n15];
      const size_t off = (size_t)(nt * 4 + n16) * 4096 + (size_t)(kt * 2 + it) * 512 +
                         kq * 128 + n15 * 8;
      *(bf16x8*)(dst + off) = v;
    }
  } else {
    const int g = b - 32;
#pragma unroll
    for (int j = 0; j < 27; ++j) s_w[t][j] = om_w[(size_t)t * 864 + g * 27 + j];
    __syncthreads();
#pragma unroll
    for (int i = 0; i < 4; ++i) {
      const int chunk = i * 256 + t;  // 1024 chunks of 8 bf16
      const int tile = chunk >> 9, ks = (chunk >> 6) & 7, kq = (chunk >> 4) & 3,
                n15 = chunk & 15;
      const int j = tile * 16 + n15;
      bf16x8 v;
#pragma unroll
      for (int cl = 0; cl < 8; ++cl) {
        const int c = ks * 32 + kq * 8 + cl;
        v[cl] = (j < 27) ? (bf16_t)s_w[c][j] : (bf16_t)0.0f;
      }
      *(bf16x8*)(om_wG + ((size_t)g << 13) + (size_t)chunk * 8) = v;
    }
  }
}

// ---------------- KF: fused dwconv3x3 + value GEMM; block = one image row ----
__global__ __launch_bounds__(512, 2) void dwconv_value_kernel(
    const float* __restrict__ x, const float* __restrict__ dw_w,
    const float* __restrict__ dw_b, const bf16_t* __restrict__ vp_wF,
    const float* __restrict__ vp_b, bf16_t* __restrict__ xdwF,
    bf16_t* __restrict__ value_g) {
  __shared__ bf16_t s_xf[64 * 256];   // x bf16 frags; reused as rotated s_out
  __shared__ bf16_t s_xdw[64 * 256];  // xdw bf16 frags (staged, coalesced out)

  const int t = threadIdx.x;
  const int row = blockIdx.x;        // img*64 + y
  const int y = row & 63;
  const int img = row >> 6;

  // ---- Phase A: dwconv -> s_xdw (LDS only; no global stores)
  {
    const int cq = (t & 63) * 4;   // channel base
    const int seg = t >> 6;        // 8-px segment
    const bool up = (y > 0), dn = (y < HH - 1);
    const float* xrow = x + (size_t)row * WW * CC + cq;

    const float4 bias = *(const float4*)&dw_b[cq];
    float4 dw[9];
#pragma unroll
    for (int i = 0; i < 9; ++i) dw[i] = *(const float4*)&dw_w[(size_t)i * CC + cq];

    const float4 zero = make_float4(0.f, 0.f, 0.f, 0.f);
    auto loadcol = [&](int xx, float4 c[3]) {
      if (xx < 0 || xx >= WW) { c[0] = c[1] = c[2] = zero; return; }
      c[0] = up ? *(const float4*)(xrow + ((size_t)xx - WW) * CC) : zero;
      c[1] = *(const float4*)(xrow + (size_t)xx * CC);
      c[2] = dn ? *(const float4*)(xrow + ((size_t)xx + WW) * CC) : zero;
    };

    const int x0 = seg * 8;
    float4 cm[3], cc[3], cp[3];
    loadcol(x0 - 1, cm);
    loadcol(x0, cc);

    for (int xx = x0; xx < x0 + 8; ++xx) {
      loadcol(xx + 1, cp);
      float4 a = bias;
#pragma unroll
      for (int r = 0; r < 3; ++r) {
        const float4 w0 = dw[r * 3 + 0], w1 = dw[r * 3 + 1], w2 = dw[r * 3 + 2];
        a.x = fmaf(cm[r].x, w0.x, fmaf(cc[r].x, w1.x, fmaf(cp[r].x, w2.x, a.x)));
        a.y = fmaf(cm[r].y, w0.y, fmaf(cc[r].y, w1.y, fmaf(cp[r].y, w2.y, a.y)));
        a.z = fmaf(cm[r].z, w0.z, fmaf(cc[r].z, w1.z, fmaf(cp[r].z, w2.z, a.z)));
        a.w = fmaf(cm[r].w, w0.w, fmaf(cc[r].w, w1.w, fmaf(cp[r].w, w2.w, a.w)));
      }
      bf16x4 av, cv;
      av[0] = (bf16_t)a.x; av[1] = (bf16_t)a.y; av[2] = (bf16_t)a.z; av[3] = (bf16_t)a.w;
      cv[0] = (bf16_t)cc[1].x; cv[1] = (bf16_t)cc[1].y;
      cv[2] = (bf16_t)cc[1].z; cv[3] = (bf16_t)cc[1].w;
      const int lf = (xx >> 4) * 4096 + ((cq >> 5) * 512) + (((cq >> 3) & 3) * 128) +
                     ((xx & 15) * 8) + (cq & 7);
      *(bf16x4*)&s_xdw[lf] = av;
      *(bf16x4*)&s_xf[lf] = cv;
#pragma unroll
      for (int r = 0; r < 3; ++r) { cm[r] = cc[r]; cc[r] = cp[r]; }
    }
  }
  __syncthreads();

  // ---- cooperative coalesced xdwF store (2048 x 16B linear)
  {
    const bf16x8* src = (const bf16x8*)s_xdw;
    bf16x8* dst = (bf16x8*)(xdwF + (size_t)row * 16384);
#pragma unroll
    for (int i = 0; i < 4; ++i) {
      const int idx = i * 512 + t;
      dst[idx] = src[idx];
    }
  }

  // ---- Phase B: value GEMM (M=64 from LDS, N=256)
  {
    const int lane = t & 63;
    const int wave = t >> 6;
    const int mq = wave >> 1;      // m-tile 0..3
    const int nh = wave & 1;       // n-half
    const int m = lane & 15;
    const int kq = lane >> 4;

    const bf16_t* Ap = s_xf + mq * 4096 + lane * 8;
    const bf16_t* Bp = vp_wF + (size_t)(nh * 8) * 4096 + lane * 8;

    f32x4 acc[8] = {};
#pragma unroll
    for (int ks = 0; ks < 8; ++ks) {
      const bf16x8 a = *(const bf16x8*)(Ap + ks * 512);
#pragma unroll
      for (int i = 0; i < 8; ++i) {
        const bf16x8 b = *(const bf16x8*)(Bp + (size_t)i * 4096 + ks * 512);
        acc[i] = __builtin_amdgcn_mfma_f32_16x16x32_bf16(a, b, acc[i], 0, 0, 0);
      }
    }

    __syncthreads();   // all waves done reading s_xf; safe to overwrite

    // rotated staging: s_out[px][((g+px)&31)*8 + c] (read-side conflict-free)
    bf16_t* s_out = s_xf;
#pragma unroll
    for (int i = 0; i < 8; ++i) {
      const int n = (nh * 8 + i) * 16 + m;
      const float bs = vp_b[n];
      const int g = n >> 3, c = n & 7;
#pragma unroll
      for (int r = 0; r < 4; ++r) {
        const int pl = mq * 16 + kq * 4 + r;           // pixel local 0..63
        s_out[pl * 256 + (((g + pl) & 31) << 3) + c] = (bf16_t)(acc[i][r] + bs);
      }
    }
  }
  __syncthreads();

  // ---- cooperative coalesced value_g store: chunk = g*64+px -> 1KB runs/g
  {
    const bf16x8* s16 = (const bf16x8*)s_xf;
    bf16x8* dst = (bf16x8*)value_g;
#pragma unroll
    for (int i = 0; i < 4; ++i) {
      const int chunk = i * 512 + t;       // 0..2047
      const int g = chunk >> 6, px = chunk & 63;
      const bf16x8 v = s16[px * 32 + ((g + px) & 31)];
      dst[((size_t)(img * G + g) << 12) + y * 64 + px] = v;
    }
  }
}

// ---------------- OMS: fused om GEMM + sampling; block = (img, g, quarter) --
// grid b: img = b&7, g = (b>>3)&31, quarter = b>>8  (R9/R19/R20 config).
// Block = 512 threads = 8 waves; each wave owns 8 m-tiles (128 px).
// LDS 135.2 KB -> 1 block/CU. om GEMM: depth-2 A-frag register dbuf (new).
__global__ __launch_bounds__(512, 2) void oms_kernel(
    const bf16_t* __restrict__ xdwF, const bf16_t* __restrict__ om_wG,
    const float* __restrict__ om_b, const bf16_t* __restrict__ value_g,
    bf16_t* __restrict__ sampledF) {
  __shared__ bf16x8 s_v[66 * 66];          // 69,696 B zero-padded value plane
  __shared__ bf16_t s_om[8][4][128][8];    // 65,536 B chunk-major, p-stride 16B

  const int t = threadIdx.x;
  const int lane = t & 63, wave = t >> 6;  // wave 0..7
  const int b = blockIdx.x;
  const int img = b & 7, g = (b >> 3) & 31, quarter = b >> 8;
  const int c15 = lane & 15, kq = lane >> 4;
  const int tile0 = img * 256 + quarter * 64;   // global 16-px-tile base

  // ---- B-frags (g's padded 32 om columns) into registers
  bf16x8 wf[2][8];
  {
    const bf16_t* base = om_wG + ((size_t)g << 13) + (size_t)lane * 8;
#pragma unroll
    for (int n2 = 0; n2 < 2; ++n2)
#pragma unroll
      for (int ks = 0; ks < 8; ++ks)
        wf[n2][ks] = *(const bf16x8*)(base + n2 * 4096 + ks * 512);
  }
  float bias[2][4];
#pragma unroll
  for (int n2 = 0; n2 < 2; ++n2)
#pragma unroll
    for (int r = 0; r < 4; ++r) {
      const int j = n2 * 16 + kq * 4 + r;
      bias[n2][r] = (j < 27) ? om_b[g * 27 + j] : 0.0f;
    }

  // ---- stage full value plane: zero border + interior
  {
    const bf16x8 zv = {};
    for (int i = t; i < 260; i += 512) {
      int Y, X;
      if (i < 66)       { Y = 0;           X = i; }
      else if (i < 132) { Y = 65;          X = i - 66; }
      else if (i < 196) { Y = i - 132 + 1; X = 0; }
      else              { Y = i - 196 + 1; X = 65; }
      s_v[Y * 66 + X] = zv;
    }
    const bf16x8* plane = (const bf16x8*)(value_g + ((size_t)(img * G + g) << 15));
#pragma unroll
    for (int i = 0; i < 8; ++i) {
      const int c = i * 512 + t;   // 0..4095
      s_v[((c >> 6) + 1) * 66 + (c & 63) + 1] = plane[c];
    }
  }

  // ---- om GEMM: 8 tiles/wave, depth-2 A-frag double buffer ----
  {
    const int tb = tile0 + wave * 8;
    const bf16_t* Abase = xdwF + (size_t)tb * 4096 + (size_t)lane * 8;

    bf16x8 xf0[8], xf1[8];
#pragma unroll
    for (int ks = 0; ks < 8; ++ks) xf0[ks] = *(const bf16x8*)(Abase + ks * 512);

#pragma unroll
    for (int q = 0; q < 8; ++q) {
      // prefetch q+1 into the other buffer before q's MFMAs
      bf16x8* cur = (q & 1) ? xf1 : xf0;
      bf16x8* nxt = (q & 1) ? xf0 : xf1;
      if (q < 7) {
        const bf16_t* Ap1 = Abase + (size_t)(q + 1) * 4096;
#pragma unroll
        for (int ks = 0; ks < 8; ++ks) nxt[ks] = *(const bf16x8*)(Ap1 + ks * 512);
      }
      f32x4 a0 = {}, a1 = {};
#pragma unroll
      for (int ks = 0; ks < 8; ++ks) {
        a0 = __builtin_amdgcn_mfma_f32_16x16x32_bf16(wf[0][ks], cur[ks], a0, 0, 0, 0);
        a1 = __builtin_amdgcn_mfma_f32_16x16x32_bf16(wf[1][ks], cur[ks], a1, 0, 0, 0);
      }
      const int p = q * 16 + c15;
      bf16x4 b0, b1;
#pragma unroll
      for (int r = 0; r < 4; ++r) {
        b0[r] = (bf16_t)(a0[r] + bias[0][r]);
        b1[r] = (bf16_t)(a1[r] + bias[1][r]);
      }
      // chunk = j>>3: n2=0 -> kq>>1, n2=1 -> 2+(kq>>1); half = kq&1
      *(bf16x4*)&s_om[wave][kq >> 1][p][(kq & 1) * 4] = b0;
      *(bf16x4*)&s_om[wave][2 + (kq >> 1)][p][(kq & 1) * 4] = b1;
    }
  }
  __syncthreads();   // s_v ready (s_om is same-wave, covered by the barrier too)

  // ---- sampling: 2 px/thread, interleaved tap chains, scalar cvt+fmaf
  {
    const int pinA = quarter * 1024 + wave * 128 + lane;  // in-image px
    const int pinB = pinA + 64;
    float arrA[27], arrB[27];
#pragma unroll
    for (int c = 0; c < 4; ++c) {
      const bf16x8 oA = *(const bf16x8*)&s_om[wave][c][lane][0];
      const bf16x8 oB = *(const bf16x8*)&s_om[wave][c][64 + lane][0];
#pragma unroll
      for (int j = 0; j < 8; ++j) {
        const int idx = c * 8 + j;
        if (idx < 27) { arrA[idx] = (float)oA[j]; arrB[idx] = (float)oB[j]; }
      }
    }
    const int xw = lane;             // pin & 63 (wave*128 is 0 mod 64)
    const int yA = (pinA >> 6) & 63;
    const int yB = yA + 1;

    float accA[GC], accB[GC];
#pragma unroll
    for (int c = 0; c < GC; ++c) { accA[c] = 0.0f; accB[c] = 0.0f; }

    auto tap = [&](const float* arr, const int y, float* acc, const int k) {
      const float pxf = (float)(xw + (k % 3) - 1) + arr[2 * k];
      const float pyf = (float)(y + (k / 3) - 1) + arr[2 * k + 1];
      const float mk = arr[18 + k];
      const float x0f = floorf(pxf), y0f = floorf(pyf);
      const float tx = pxf - x0f, ty = pyf - y0f;
      const int ix = (int)x0f, iy = (int)y0f;

      // clamp to padded range [-1,64]; border zeros kill OOB contributions
      const int iX0 = min(max(ix, -1), 64) + 1;
      const int iX1 = min(max(ix + 1, -1), 64) + 1;
      const int iY0 = min(max(iy, -1), 64) + 1;
      const int iY1 = min(max(iy + 1, -1), 64) + 1;

      const bf16x8 v00 = s_v[iY0 * 66 + iX0];
      const bf16x8 v01 = s_v[iY0 * 66 + iX1];
      const bf16x8 v10 = s_v[iY1 * 66 + iX0];
      const bf16x8 v11 = s_v[iY1 * 66 + iX1];

      const float w00 = mk * (1.0f - ty) * (1.0f - tx);
      const float w01 = mk * (1.0f - ty) * tx;
      const float w10 = mk * ty * (1.0f - tx);
      const float w11 = mk * ty * tx;

#pragma unroll
      for (int c = 0; c < GC; ++c) {
        float s = acc[c];
        s = fmaf(w00, (float)v00[c], s);
        s = fmaf(w01, (float)v01[c], s);
        s = fmaf(w10, (float)v10[c], s);
        s = fmaf(w11, (float)v11[c], s);
        acc[c] = s;
      }
    };

#pragma unroll
    for (int k = 0; k < 9; ++k) {
      tap(arrA, yA, accA, k);
      tap(arrB, yB, accB, k);
    }

    bf16x8 svA, svB;
#pragma unroll
    for (int c = 0; c < GC; ++c) {
      svA[c] = (bf16_t)accA[c];
      svB[c] = (bf16_t)accB[c];
    }
    *(bf16x8*)(sampledF + fragIdx(img * 4096 + pinA, g * 8)) = svA;
    *(bf16x8*)(sampledF + fragIdx(img * 4096 + pinB, g * 8)) = svB;
  }
}

// ---------------- K4: out = sampledF @ op_wF, M=128/block, B in LDS ----------
__global__ __launch_bounds__(1024, 1) void out_gemm_kernel(
    const bf16_t* __restrict__ AF, const bf16_t* __restrict__ BF,
    float* __restrict__ out) {
  __shared__ bf16_t s_b[CC * CC];  // 131,072 B: full B, frag layout (linear copy)

  const int t = threadIdx.x;
  {
    const bf16x8* src = (const bf16x8*)BF;
    bf16x8* dst = (bf16x8*)s_b;
#pragma unroll
    for (int i = 0; i < 8; ++i) dst[i * 1024 + t] = src[i * 1024 + t];
  }
  __syncthreads();

  const int lane = t & 63;
  const int wave = t >> 6;        // 0..15
  const int mq = wave >> 1;       // m-tile 0..7
  const int nh = wave & 1;        // n-half
  const int mt = blockIdx.x * 8 + mq;
  const int m = lane & 15;
  const int kq = lane >> 4;

  const bf16_t* Ap = AF + (size_t)mt * 4096 + lane * 8;
  const bf16_t* Bp = s_b + (size_t)(nh * 8) * 4096 + lane * 8;

  f32x4 acc[8] = {};
#pragma unroll
  for (int ks = 0; ks < 8; ++ks) {
    const bf16x8 a = *(const bf16x8*)(Ap + ks * 512);
#pragma unroll
    for (int i = 0; i < 8; ++i) {
      const bf16x8 b = *(const bf16x8*)(Bp + (size_t)i * 4096 + ks * 512);
      acc[i] = __builtin_amdgcn_mfma_f32_16x16x32_bf16(a, b, acc[i], 0, 0, 0);
    }
  }

#pragma unroll
  for (int i = 0; i < 8; ++i) {
    const int n = (nh * 8 + i) * 16 + m;
#pragma unroll
    for (int r = 0; r < 4; ++r) {
      const int pix = mt * 16 + kq * 4 + r;
      out[(size_t)pix * CC + n] = acc[i][r];
    }
  }
}

extern "C" void kernel_launch(void* const* d_in, const int* in_sizes, int n_in,
                              void* d_out, int out_size, void* d_ws, size_t ws_size,
                              hipStream_t stream) {
  const float* x = (const float*)d_in[0];
  const float* dw_w = (const float*)d_in[1];
  const float* dw_b = (const float*)d_in[2];
  const float* om_w = (const float*)d_in[3];
  const float* om_b = (const float*)d_in[4];
  const float* vp_w = (const float*)d_in[5];
  const float* vp_b = (const float*)d_in[6];
  const float* op_w = (const float*)d_in[7];
  float* out = (float*)d_out;

  // workspace layout (bytes)
  char* ws = (char*)d_ws;
  bf16_t* value_g = (bf16_t*)ws;                      // 16,777,216
  bf16_t* xdwF = (bf16_t*)(ws + 16777216);            // 16,777,216
  bf16_t* sampledF = (bf16_t*)(ws + 33554432);        // 16,777,216
  bf16_t* om_wG = (bf16_t*)(ws + 50331648);           //    524,288
  bf16_t* vp_wF = (bf16_t*)(ws + 50855936);           //    131,072
  bf16_t* op_wF = (bf16_t*)(ws + 50987008);           //    131,072

  convert_weights_kernel<<<64, 256, 0, stream>>>(om_w, vp_w, op_w,
                                                 om_wG, vp_wF, op_wF);
  dwconv_value_kernel<<<NN * HH, 512, 0, stream>>>(x, dw_w, dw_b, vp_wF, vp_b,
                                                   xdwF, value_g);
  oms_kernel<<<1024, 512, 0, stream>>>(xdwF, om_wG, om_b, value_g, sampledF);
  out_gemm_kernel<<<NPIX / 128, 1024, 0, stream>>>(sampledF, op_wF, out);
}